// Round 1
// baseline (52480.353 us; speedup 1.0000x reference)
//
#include <hip/hip_runtime.h>

#define T_STEPS 4096
#define HD 2048
#define G4 8192
#define NWG 256
#define NTH 512

typedef __attribute__((ext_vector_type(8))) short bf16x8;
typedef __attribute__((ext_vector_type(4))) float f32x4;
typedef __attribute__((ext_vector_type(8))) unsigned short u16x8;

static __device__ __forceinline__ unsigned short f2bf(float f){
  union { float f; unsigned int u; } v; v.f = f;
  unsigned int r = (v.u + 0x7fffu + ((v.u >> 16) & 1u)) >> 16;
  return (unsigned short)r;
}
static __device__ __forceinline__ float bf2f(unsigned short s){
  union { unsigned int u; float f; } v; v.u = ((unsigned int)s) << 16;
  return v.f;
}

// ---------------- init: bias fuse + zero h0 + zero counters ----------------
__global__ void init_kernel(const float* __restrict__ b_ih, const float* __restrict__ b_hh,
                            float* __restrict__ bias, float* __restrict__ Hrow0,
                            int* __restrict__ r1, int* __restrict__ r2){
  int i = blockIdx.x*blockDim.x + threadIdx.x;
  int stride = gridDim.x*blockDim.x;
  const int NTOT = G4 + HD + 8*T_STEPS + T_STEPS;
  for (int idx = i; idx < NTOT; idx += stride){
    if (idx < G4) bias[idx] = b_ih[idx] + b_hh[idx];
    else if (idx < G4+HD) Hrow0[idx-G4] = 0.f;
    else if (idx < G4+HD+8*T_STEPS) r1[idx-G4-HD] = 0;
    else r2[idx-G4-HD-8*T_STEPS] = 0;
  }
}

// ---------------- phase 1: XP = x @ W_ih^T + (b_ih+b_hh), bf16 out ----------------
__global__ __launch_bounds__(256) void gemm_xp(const float* __restrict__ X,
                                               const float* __restrict__ W,
                                               const float* __restrict__ bias,
                                               unsigned short* __restrict__ XP){
  __shared__ __align__(16) unsigned short As[128][40];
  __shared__ __align__(16) unsigned short Bs[128][40];
  const int tid = threadIdx.x;
  const int bx = blockIdx.x & 63;   // 8192/128 = 64 col tiles (j)
  const int by = blockIdx.x >> 6;   // 4096/128 = 32 row tiles (t)
  const int row0 = by*128, col0 = bx*128;
  const int l = tid & 63, w = tid >> 6;
  const int wrow = (w>>1)*64, wcol = (w&1)*64;
  const int lr = l & 15, lk = l >> 4;

  f32x4 acc[4][4];
  #pragma unroll
  for (int mi=0; mi<4; mi++)
    #pragma unroll
    for (int ni=0; ni<4; ni++)
      acc[mi][ni] = (f32x4){0.f,0.f,0.f,0.f};

  const int sr = tid >> 1;          // staged row 0..127
  const int sh = (tid & 1) * 16;    // k half
  const float* xb = X + (size_t)(row0+sr)*2048 + sh;
  const float* wb = W + (size_t)(col0+sr)*2048 + sh;

  for (int k0 = 0; k0 < 2048; k0 += 32){
    __syncthreads();
    u16x8 va[2], vb[2];
    #pragma unroll
    for (int q=0; q<2; q++){
      float4 u = *(const float4*)(xb + k0 + q*8);
      float4 v = *(const float4*)(xb + k0 + q*8 + 4);
      u16x8 t;
      t[0]=f2bf(u.x); t[1]=f2bf(u.y); t[2]=f2bf(u.z); t[3]=f2bf(u.w);
      t[4]=f2bf(v.x); t[5]=f2bf(v.y); t[6]=f2bf(v.z); t[7]=f2bf(v.w);
      va[q]=t;
      float4 p = *(const float4*)(wb + k0 + q*8);
      float4 r = *(const float4*)(wb + k0 + q*8 + 4);
      u16x8 s;
      s[0]=f2bf(p.x); s[1]=f2bf(p.y); s[2]=f2bf(p.z); s[3]=f2bf(p.w);
      s[4]=f2bf(r.x); s[5]=f2bf(r.y); s[6]=f2bf(r.z); s[7]=f2bf(r.w);
      vb[q]=s;
    }
    *(u16x8*)&As[sr][sh]   = va[0];
    *(u16x8*)&As[sr][sh+8] = va[1];
    *(u16x8*)&Bs[sr][sh]   = vb[0];
    *(u16x8*)&Bs[sr][sh+8] = vb[1];
    __syncthreads();

    bf16x8 af[4], bfr[4];
    #pragma unroll
    for (int mi=0; mi<4; mi++) af[mi]  = *(const bf16x8*)&As[wrow+mi*16+lr][lk*8];
    #pragma unroll
    for (int ni=0; ni<4; ni++) bfr[ni] = *(const bf16x8*)&Bs[wcol+ni*16+lr][lk*8];
    #pragma unroll
    for (int mi=0; mi<4; mi++)
      #pragma unroll
      for (int ni=0; ni<4; ni++)
        acc[mi][ni] = __builtin_amdgcn_mfma_f32_16x16x32_bf16(af[mi], bfr[ni], acc[mi][ni], 0,0,0);
  }

  #pragma unroll
  for (int ni=0; ni<4; ni++){
    const int jc = col0 + wcol + ni*16 + lr;
    const float bv = bias[jc];
    #pragma unroll
    for (int mi=0; mi<4; mi++){
      const int tr0 = row0 + wrow + mi*16 + lk*4;
      #pragma unroll
      for (int r=0; r<4; r++)
        XP[(size_t)(tr0+r)*G4 + jc] = f2bf(acc[mi][ni][r] + bv);
    }
  }
}

// ---------------- phase 2: persistent LSTM recurrence ----------------
// 256 WGs x 512 thr. WG g owns h-dims [8g, 8g+8). W_hh rows for those dims
// (32 rows x 2048 k, fp32) live in REGISTERS: wave w holds rows rr=4w..4w+3,
// lane l holds k in {c*512 + 8l .. +8}. Row index rr = gate*8 + dd.
__global__ __launch_bounds__(512, 2) void recur(const unsigned short* __restrict__ XP,
                                                const float* __restrict__ Whh,
                                                float* __restrict__ Hbuf,
                                                int* __restrict__ r1,
                                                int* __restrict__ r2){
  __shared__ float h_lds[HD];
  __shared__ float gsum[32];
  __shared__ float xp_s[32];
  __shared__ float c_lds[8];
  const int g = blockIdx.x;
  const int tid = threadIdx.x;
  const int l = tid & 63, w = tid >> 6;

  float wr[4][4][8];
  #pragma unroll
  for (int ri=0; ri<4; ri++){
    const int rr = w*4 + ri;
    const int jg = (rr>>3)*HD + g*8 + (rr&7);
    const float* wp = Whh + (size_t)jg*HD + l*8;
    #pragma unroll
    for (int c=0; c<4; c++){
      float4 lo = *(const float4*)(wp + c*512);
      float4 hi = *(const float4*)(wp + c*512 + 4);
      wr[ri][c][0]=lo.x; wr[ri][c][1]=lo.y; wr[ri][c][2]=lo.z; wr[ri][c][3]=lo.w;
      wr[ri][c][4]=hi.x; wr[ri][c][5]=hi.y; wr[ri][c][6]=hi.z; wr[ri][c][7]=hi.w;
    }
  }
  if (tid < 8) c_lds[tid] = 0.f;

  for (int t=0; t<T_STEPS; t++){
    // prefetch this step's input-projection slice (independent of h)
    if (tid < 32){
      const int jc = (tid>>3)*HD + g*8 + (tid&7);
      xp_s[tid] = bf2f(XP[(size_t)t*G4 + jc]);
    }
    // wait for h[t-1] from all 256 WGs
    if (tid == 0 && t > 0){
      while (__hip_atomic_load(&r2[t-1], __ATOMIC_RELAXED, __HIP_MEMORY_SCOPE_AGENT) < 8)
        __builtin_amdgcn_s_sleep(2);
      __builtin_amdgcn_fence(__ATOMIC_ACQUIRE, "agent");
    }
    __syncthreads();
    // stage h[t-1] (row t; row 0 is zeros) into LDS
    *(float4*)&h_lds[tid*4] = *(const float4*)(Hbuf + (size_t)t*HD + tid*4);
    __syncthreads();

    // gates partials: 4 rows x 32 k per lane, all from registers
    float acc[4] = {0.f,0.f,0.f,0.f};
    #pragma unroll
    for (int c=0; c<4; c++){
      float4 h0 = *(const float4*)&h_lds[c*512 + l*8];
      float4 h1 = *(const float4*)&h_lds[c*512 + l*8 + 4];
      float hv[8] = {h0.x,h0.y,h0.z,h0.w,h1.x,h1.y,h1.z,h1.w};
      #pragma unroll
      for (int ri=0; ri<4; ri++)
        #pragma unroll
        for (int e=0; e<8; e++)
          acc[ri] += wr[ri][c][e]*hv[e];
    }
    #pragma unroll
    for (int ri=0; ri<4; ri++){
      float s = acc[ri];
      #pragma unroll
      for (int off=32; off; off>>=1) s += __shfl_xor(s, off, 64);
      if (l == 0) gsum[w*4+ri] = s;
    }
    __syncthreads();

    // cell update: lanes 0..7 (wave 0), dim dd = tid
    if (tid < 8){
      float ipre = gsum[tid]    + xp_s[tid];
      float fpre = gsum[8+tid]  + xp_s[8+tid];
      float gpre = gsum[16+tid] + xp_s[16+tid];
      float opre = gsum[24+tid] + xp_s[24+tid];
      float iv = 1.f/(1.f + __expf(-ipre));
      float fv = 1.f/(1.f + __expf(-fpre));
      float e2 = __expf(-2.f*gpre);
      float gv = (1.f - e2)/(1.f + e2);
      float ov = 1.f/(1.f + __expf(-opre));
      float cc = fv*c_lds[tid] + iv*gv;
      c_lds[tid] = cc;
      float e2c = __expf(-2.f*cc);
      float th = (1.f - e2c)/(1.f + e2c);
      Hbuf[(size_t)(t+1)*HD + g*8 + tid] = ov*th;
    }
    // publish: release h-chunk, two-level counter (32 per group, 8 groups)
    if (tid == 0){
      __threadfence();
      int old = __hip_atomic_fetch_add(&r1[t*8 + (g&7)], 1, __ATOMIC_ACQ_REL, __HIP_MEMORY_SCOPE_AGENT);
      if (old == 31)
        __hip_atomic_fetch_add(&r2[t], 1, __ATOMIC_ACQ_REL, __HIP_MEMORY_SCOPE_AGENT);
    }
  }
}

// ---------------- phase 3: y[t] = h_t . W_out + b_out ----------------
__global__ __launch_bounds__(256) void out_gemv(const float* __restrict__ Hbuf,
                                                const float* __restrict__ Wout,
                                                const float* __restrict__ bout,
                                                float* __restrict__ y){
  const int t = blockIdx.x;
  const int tid = threadIdx.x;
  const float* h = Hbuf + (size_t)(t+1)*HD;
  float4 a0 = *(const float4*)(h + tid*8);
  float4 a1 = *(const float4*)(h + tid*8 + 4);
  float4 w0 = *(const float4*)(Wout + tid*8);
  float4 w1 = *(const float4*)(Wout + tid*8 + 4);
  float s = a0.x*w0.x + a0.y*w0.y + a0.z*w0.z + a0.w*w0.w
          + a1.x*w1.x + a1.y*w1.y + a1.z*w1.z + a1.w*w1.w;
  #pragma unroll
  for (int off=32; off; off>>=1) s += __shfl_xor(s, off, 64);
  __shared__ float ps[4];
  if ((tid & 63) == 0) ps[tid>>6] = s;
  __syncthreads();
  if (tid == 0) y[t] = ps[0]+ps[1]+ps[2]+ps[3] + bout[0];
}

extern "C" void kernel_launch(void* const* d_in, const int* in_sizes, int n_in,
                              void* d_out, int out_size, void* d_ws, size_t ws_size,
                              hipStream_t stream) {
  const float* x    = (const float*)d_in[0];
  const float* Wih  = (const float*)d_in[1];
  const float* Whh  = (const float*)d_in[2];
  const float* b_ih = (const float*)d_in[3];
  const float* b_hh = (const float*)d_in[4];
  const float* Wout = (const float*)d_in[5];
  const float* bout = (const float*)d_in[6];
  float* y = (float*)d_out;

  char* ws = (char*)d_ws;
  unsigned short* XP = (unsigned short*)(ws);                 // 4096*8192*2  = 67108864
  float* Hbuf        = (float*)(ws + 67108864);               // 4097*2048*4  = 33562624
  float* bias        = (float*)(ws + 100671488);              // 8192*4       = 32768
  int* r1            = (int*)(ws + 100704256);                // 4096*8*4     = 131072
  int* r2            = (int*)(ws + 100835328);                // 4096*4       = 16384

  init_kernel<<<64, 256, 0, stream>>>(b_ih, b_hh, bias, Hbuf, r1, r2);
  gemm_xp<<<2048, 256, 0, stream>>>(x, Wih, bias, XP);

  void* args[] = {(void*)&XP, (void*)&Whh, (void*)&Hbuf, (void*)&r1, (void*)&r2};
  hipLaunchCooperativeKernel((void*)recur, dim3(NWG), dim3(NTH), args, 0, stream);

  out_gemv<<<T_STEPS, 256, 0, stream>>>(Hbuf, Wout, bout, y);
}

// Round 2
// 10532.721 us; speedup vs baseline: 4.9826x; 4.9826x over previous
//
#include <hip/hip_runtime.h>

#define T_STEPS 4096
#define HD 2048
#define G4 8192
#define NWG 256
#define NTH 1024
#define SENT 0x7FC0DEADu

typedef __attribute__((ext_vector_type(8))) short bf16x8;
typedef __attribute__((ext_vector_type(4))) float f32x4;
typedef __attribute__((ext_vector_type(2))) float f32x2;
typedef __attribute__((ext_vector_type(8))) unsigned short u16x8;

static __device__ __forceinline__ unsigned short f2bf(float f){
  union { float f; unsigned int u; } v; v.f = f;
  unsigned int r = (v.u + 0x7fffu + ((v.u >> 16) & 1u)) >> 16;
  return (unsigned short)r;
}
static __device__ __forceinline__ float bf2f(unsigned short s){
  union { unsigned int u; float f; } v; v.u = ((unsigned int)s) << 16;
  return v.f;
}

// uncached (coherence-point) 8B load — bypasses L1/L2 so no fences needed
static __device__ __forceinline__ f32x2 ld2_uc(const float* p){
  f32x2 r;
  asm volatile("global_load_dwordx2 %0, %1, off sc0 sc1\n\ts_waitcnt vmcnt(0)"
               : "=v"(r) : "v"(p) : "memory");
  return r;
}
// write-through 4B store
static __device__ __forceinline__ void st_uc(float* p, float v){
  asm volatile("global_store_dword %0, %1, off sc0 sc1" :: "v"(p), "v"(v) : "memory");
}

// ---------------- init: bias fuse + h0 zeros + sentinel rows ----------------
__global__ void init_kernel(const float* __restrict__ b_ih, const float* __restrict__ b_hh,
                            float* __restrict__ bias, float* __restrict__ Hbuf){
  int i = blockIdx.x*blockDim.x + threadIdx.x;
  int stride = gridDim.x*blockDim.x;
  const int NTOT = G4 + (T_STEPS+1)*HD;
  union { unsigned int u; float f; } sent; sent.u = SENT;
  for (int idx = i; idx < NTOT; idx += stride){
    if (idx < G4) bias[idx] = b_ih[idx] + b_hh[idx];
    else {
      int j = idx - G4;
      Hbuf[j] = (j < HD) ? 0.f : sent.f;
    }
  }
}

// ---------------- phase 1: XP = x @ W_ih^T + (b_ih+b_hh), bf16 out ----------------
__global__ __launch_bounds__(256) void gemm_xp(const float* __restrict__ X,
                                               const float* __restrict__ W,
                                               const float* __restrict__ bias,
                                               unsigned short* __restrict__ XP){
  __shared__ __align__(16) unsigned short As[128][40];
  __shared__ __align__(16) unsigned short Bs[128][40];
  const int tid = threadIdx.x;
  const int bx = blockIdx.x & 63;
  const int by = blockIdx.x >> 6;
  const int row0 = by*128, col0 = bx*128;
  const int l = tid & 63, w = tid >> 6;
  const int wrow = (w>>1)*64, wcol = (w&1)*64;
  const int lr = l & 15, lk = l >> 4;

  f32x4 acc[4][4];
  #pragma unroll
  for (int mi=0; mi<4; mi++)
    #pragma unroll
    for (int ni=0; ni<4; ni++)
      acc[mi][ni] = (f32x4){0.f,0.f,0.f,0.f};

  const int sr = tid >> 1;
  const int sh = (tid & 1) * 16;
  const float* xb = X + (size_t)(row0+sr)*2048 + sh;
  const float* wb = W + (size_t)(col0+sr)*2048 + sh;

  for (int k0 = 0; k0 < 2048; k0 += 32){
    __syncthreads();
    u16x8 va[2], vb[2];
    #pragma unroll
    for (int q=0; q<2; q++){
      float4 u = *(const float4*)(xb + k0 + q*8);
      float4 v = *(const float4*)(xb + k0 + q*8 + 4);
      u16x8 t;
      t[0]=f2bf(u.x); t[1]=f2bf(u.y); t[2]=f2bf(u.z); t[3]=f2bf(u.w);
      t[4]=f2bf(v.x); t[5]=f2bf(v.y); t[6]=f2bf(v.z); t[7]=f2bf(v.w);
      va[q]=t;
      float4 p = *(const float4*)(wb + k0 + q*8);
      float4 r = *(const float4*)(wb + k0 + q*8 + 4);
      u16x8 s;
      s[0]=f2bf(p.x); s[1]=f2bf(p.y); s[2]=f2bf(p.z); s[3]=f2bf(p.w);
      s[4]=f2bf(r.x); s[5]=f2bf(r.y); s[6]=f2bf(r.z); s[7]=f2bf(r.w);
      vb[q]=s;
    }
    *(u16x8*)&As[sr][sh]   = va[0];
    *(u16x8*)&As[sr][sh+8] = va[1];
    *(u16x8*)&Bs[sr][sh]   = vb[0];
    *(u16x8*)&Bs[sr][sh+8] = vb[1];
    __syncthreads();

    bf16x8 af[4], bfr[4];
    #pragma unroll
    for (int mi=0; mi<4; mi++) af[mi]  = *(const bf16x8*)&As[wrow+mi*16+lr][lk*8];
    #pragma unroll
    for (int ni=0; ni<4; ni++) bfr[ni] = *(const bf16x8*)&Bs[wcol+ni*16+lr][lk*8];
    #pragma unroll
    for (int mi=0; mi<4; mi++)
      #pragma unroll
      for (int ni=0; ni<4; ni++)
        acc[mi][ni] = __builtin_amdgcn_mfma_f32_16x16x32_bf16(af[mi], bfr[ni], acc[mi][ni], 0,0,0);
  }

  #pragma unroll
  for (int ni=0; ni<4; ni++){
    const int jc = col0 + wcol + ni*16 + lr;
    const float bv = bias[jc];
    #pragma unroll
    for (int mi=0; mi<4; mi++){
      const int tr0 = row0 + wrow + mi*16 + lk*4;
      #pragma unroll
      for (int r=0; r<4; r++)
        XP[(size_t)(tr0+r)*G4 + jc] = f2bf(acc[mi][ni][r] + bv);
    }
  }
}

// ---------------- phase 2: persistent LSTM recurrence ----------------
// 256 WGs x 1024 thr (16 waves). WG g owns h-dims [8g,8g+8) = 32 gate rows.
// Wave w owns rows rr=2w,2w+1 (rr = gate*8 + dd). Lane l covers
// k in {c*256 + 4l .. +4 : c=0..7} -> 64 fp32 weights pinned in VGPRs.
// Sync: NO fences/atomics. Producers write h via write-through (sc0 sc1)
// stores; consumers spin on uncached dwordx2 until non-sentinel.
__global__ __launch_bounds__(NTH, 4) void recur(const unsigned short* __restrict__ XP,
                                                const float* __restrict__ Whh,
                                                float* __restrict__ Hbuf){
  __shared__ float h_lds[HD];
  __shared__ float gsum[32];
  __shared__ float xp_s[32];
  const int g = blockIdx.x;
  const int tid = threadIdx.x;
  const int l = tid & 63, w = tid >> 6;

  // load + pin weights: wv[ri][c][e] = Whh[row(2w+ri)][c*256 + l*4 + e]
  float wv[2][8][4];
  #pragma unroll
  for (int ri=0; ri<2; ri++){
    const int rr = 2*w + ri;
    const size_t jrow = (size_t)(rr>>3)*HD + g*8 + (rr&7);
    const float* wp = Whh + jrow*HD + l*4;
    #pragma unroll
    for (int c=0; c<8; c++){
      float4 t4 = *(const float4*)(wp + c*256);
      wv[ri][c][0]=t4.x; wv[ri][c][1]=t4.y; wv[ri][c][2]=t4.z; wv[ri][c][3]=t4.w;
      asm volatile("" : "+v"(wv[ri][c][0]), "+v"(wv[ri][c][1]),
                        "+v"(wv[ri][c][2]), "+v"(wv[ri][c][3]));
    }
  }

  float c_reg = 0.f;  // cell state, lanes tid<8 only

  for (int t=0; t<T_STEPS; ++t){
    // this step's input-projection slice (wave 0, lanes 0..31) — cached load
    if (tid < 32)
      xp_s[tid] = bf2f(XP[(size_t)t*G4 + (size_t)(tid>>3)*HD + g*8 + (tid&7)]);

    // spin-wait on own 8B of h[t-1] (row t; row 0 = zeros)
    const float* hp = Hbuf + (size_t)t*HD + tid*2;
    f32x2 hv;
    do {
      hv = ld2_uc(hp);
    } while (__float_as_uint(hv[0]) == SENT || __float_as_uint(hv[1]) == SENT);
    *(f32x2*)&h_lds[tid*2] = hv;
    __syncthreads();

    // 2 rows x 32 k per lane, weights from registers, h from LDS (conflict-free)
    float a0 = 0.f, a1 = 0.f;
    #pragma unroll
    for (int c=0; c<8; c++){
      float4 h4 = *(const float4*)&h_lds[c*256 + l*4];
      a0 += wv[0][c][0]*h4.x + wv[0][c][1]*h4.y + wv[0][c][2]*h4.z + wv[0][c][3]*h4.w;
      a1 += wv[1][c][0]*h4.x + wv[1][c][1]*h4.y + wv[1][c][2]*h4.z + wv[1][c][3]*h4.w;
    }
    #pragma unroll
    for (int off=32; off; off>>=1){
      a0 += __shfl_xor(a0, off, 64);
      a1 += __shfl_xor(a1, off, 64);
    }
    if (l == 0){ gsum[2*w] = a0; gsum[2*w+1] = a1; }
    __syncthreads();

    // cell update + publish (lanes 0..7 of wave 0)
    if (tid < 8){
      float ipre = gsum[tid]    + xp_s[tid];
      float fpre = gsum[8+tid]  + xp_s[8+tid];
      float gpre = gsum[16+tid] + xp_s[16+tid];
      float opre = gsum[24+tid] + xp_s[24+tid];
      float iv = 1.f/(1.f + __expf(-ipre));
      float fv = 1.f/(1.f + __expf(-fpre));
      float e2 = __expf(-2.f*gpre);
      float gv = (1.f - e2)/(1.f + e2);
      float ov = 1.f/(1.f + __expf(-opre));
      c_reg = fv*c_reg + iv*gv;
      float e2c = __expf(-2.f*c_reg);
      float th = (1.f - e2c)/(1.f + e2c);
      st_uc(Hbuf + (size_t)(t+1)*HD + g*8 + tid, ov*th);
    }
  }
}

// ---------------- phase 3: y[t] = h_t . W_out + b_out ----------------
__global__ __launch_bounds__(256) void out_gemv(const float* __restrict__ Hbuf,
                                                const float* __restrict__ Wout,
                                                const float* __restrict__ bout,
                                                float* __restrict__ y){
  const int t = blockIdx.x;
  const int tid = threadIdx.x;
  const float* h = Hbuf + (size_t)(t+1)*HD;
  float4 a0 = *(const float4*)(h + tid*8);
  float4 a1 = *(const float4*)(h + tid*8 + 4);
  float4 w0 = *(const float4*)(Wout + tid*8);
  float4 w1 = *(const float4*)(Wout + tid*8 + 4);
  float s = a0.x*w0.x + a0.y*w0.y + a0.z*w0.z + a0.w*w0.w
          + a1.x*w1.x + a1.y*w1.y + a1.z*w1.z + a1.w*w1.w;
  #pragma unroll
  for (int off=32; off; off>>=1) s += __shfl_xor(s, off, 64);
  __shared__ float ps[4];
  if ((tid & 63) == 0) ps[tid>>6] = s;
  __syncthreads();
  if (tid == 0) y[t] = ps[0]+ps[1]+ps[2]+ps[3] + bout[0];
}

extern "C" void kernel_launch(void* const* d_in, const int* in_sizes, int n_in,
                              void* d_out, int out_size, void* d_ws, size_t ws_size,
                              hipStream_t stream) {
  const float* x    = (const float*)d_in[0];
  const float* Wih  = (const float*)d_in[1];
  const float* Whh  = (const float*)d_in[2];
  const float* b_ih = (const float*)d_in[3];
  const float* b_hh = (const float*)d_in[4];
  const float* Wout = (const float*)d_in[5];
  const float* bout = (const float*)d_in[6];
  float* y = (float*)d_out;

  char* ws = (char*)d_ws;
  unsigned short* XP = (unsigned short*)(ws);                 // 4096*8192*2  = 67108864
  float* Hbuf        = (float*)(ws + 67108864);               // 4097*2048*4  = 33562624
  float* bias        = (float*)(ws + 100671488);              // 8192*4       = 32768

  init_kernel<<<2048, 256, 0, stream>>>(b_ih, b_hh, bias, Hbuf);
  gemm_xp<<<2048, 256, 0, stream>>>(x, Wih, bias, XP);

  void* args[] = {(void*)&XP, (void*)&Whh, (void*)&Hbuf};
  hipLaunchCooperativeKernel((void*)recur, dim3(NWG), dim3(NTH), args, 0, stream);

  out_gemv<<<T_STEPS, 256, 0, stream>>>(Hbuf, Wout, bout, y);
}